// Round 5
// baseline (553.002 us; speedup 1.0000x reference)
//
#include <hip/hip_runtime.h>
#include <math.h>

typedef unsigned short u16;
typedef unsigned int   u32;
typedef unsigned long long u64;

#define Bb   2
#define Cc   19
#define Hh   128
#define Ww   128
#define CHc  64
#define HWs  16384
#define NPIX 32768
#define EPSf 1e-8f
#define FSTR 72               // half stride for features (64 real + 8 zero pad), 144 B
#define PSTR 24               // half stride for probs (19 real + 5 zero pad), 48 B
#define STBLK 4096            // st grid (512 threads / 8 waves per block)

typedef _Float16 h2 __attribute__((ext_vector_type(2)));

__device__ inline float fd(u32 a, u32 b, float c) {
  h2 ha = __builtin_bit_cast(h2, a);
  h2 hb = __builtin_bit_cast(h2, b);
#if __has_builtin(__builtin_amdgcn_fdot2)
  return __builtin_amdgcn_fdot2(ha, hb, c, false);
#else
  return c + (float)ha[0] * (float)hb[0] + (float)ha[1] * (float)hb[1];
#endif
}

__device__ inline u32 pk(float a, float b) {
  h2 h; h[0] = (_Float16)a; h[1] = (_Float16)b;
  return __builtin_bit_cast(u32, h);
}

// ---------- PRE: feat normalize+transpose (blocks 0..1023) | softmax (1024..1151) ----------
__global__ __launch_bounds__(256) void pre_kernel(
    const float* __restrict__ logits,
    const float* __restrict__ xsrc, const float* __restrict__ xema,
    u16* __restrict__ osrc, u16* __restrict__ oema, u16* __restrict__ pt) {
  __shared__ float smem[5376];
  int bid = blockIdx.x;
  int t = threadIdx.x;

  if (bid < 1024) {
    float* tile = smem;                 // 64*65
    float* part = smem + 4160;          // 256
    float* invn = smem + 4416;          // 64
    int xb = bid & 255, b = (bid >> 8) & 1, z = bid >> 9;
    const float* in = z ? xema : xsrc;
    u16* out = z ? oema : osrc;
    int pix0 = xb * 64;
    int w = t >> 6, l = t & 63;

    const float* src = in + (size_t)b * CHc * HWs + pix0;
#pragma unroll
    for (int cc = 0; cc < 16; cc++) {
      int c = cc * 4 + w;
      tile[c * 65 + l] = src[(size_t)c * HWs + l];
    }
    __syncthreads();
    float s = 0.f;
#pragma unroll
    for (int c = w * 16; c < w * 16 + 16; c++) { float a = tile[c * 65 + l]; s += a * a; }
    part[w * 64 + l] = s;
    __syncthreads();
    if (t < 64) {
      float n = part[t] + part[64 + t] + part[128 + t] + part[192 + t];
      invn[t] = 1.0f / fmaxf(sqrtf(n), EPSf);
    }
    __syncthreads();
    for (int i = t; i < 576; i += 256) {
      int px = i / 9, q = i - px * 9;
      float iv = invn[px];
      float v[8];
#pragma unroll
      for (int k = 0; k < 8; k++) {
        int c = q * 8 + k;
        v[k] = (c < CHc) ? tile[c * 65 + px] * iv : 0.f;
      }
      uint4 u = make_uint4(pk(v[0], v[1]), pk(v[2], v[3]), pk(v[4], v[5]), pk(v[6], v[7]));
      *((uint4*)(out + (size_t)(b * HWs + pix0 + px) * FSTR) + q) = u;
    }
  } else {
    float* lp = smem;                   // 256*21
    int pb = bid - 1024;
    int gpix = pb * 256 + t;
    int b = gpix >> 14, hw = gpix & (HWs - 1);
    const float* lg = logits + (size_t)b * Cc * HWs + hw;
    float v[Cc]; float m = -INFINITY;
#pragma unroll
    for (int c = 0; c < Cc; c++) { v[c] = lg[(size_t)c * HWs]; m = fmaxf(m, v[c]); }
    float s = 0.f;
#pragma unroll
    for (int c = 0; c < Cc; c++) { v[c] = expf(v[c] - m); s += v[c]; }
    float inv = 1.0f / s;
#pragma unroll
    for (int c = 0; c < Cc; c++) lp[t * 21 + c] = v[c] * inv;
    __syncthreads();
    u16* ob = pt + (size_t)pb * 256 * PSTR;
    for (int i = t; i < 768; i += 256) {
      int px = i / 3, q = i - px * 3;
      float v8[8];
#pragma unroll
      for (int k = 0; k < 8; k++) {
        int c = q * 8 + k;
        v8[k] = (c < Cc) ? lp[px * 21 + c] : 0.f;
      }
      uint4 u = make_uint4(pk(v8[0], v8[1]), pk(v8[2], v8[3]), pk(v8[4], v8[5]), pk(v8[6], v8[7]));
      *((uint4*)(ob + (size_t)px * PSTR) + q) = u;
    }
  }
}

// ---------- ST: fused src-sim + trg rank-select + last-block finish ----------
__global__ __launch_bounds__(512) void st_kernel(
    const u16* __restrict__ fsrc, const u16* __restrict__ fema,
    const u16* __restrict__ pt, const int* __restrict__ gt,
    const float* __restrict__ mix, float* __restrict__ partials,
    u32* __restrict__ ticket, float* __restrict__ out) {
  __shared__ u64 ksh[8][66];
  __shared__ float sacc[8][8];
  __shared__ u32 is_last;
  int bid = blockIdx.x;
  int swz = ((bid & 7) << 9) | (bid >> 3);         // 4096 % 8 == 0: bijective
  int t = threadIdx.x, wv = t >> 6, lane = t & 63;
  int pix = __builtin_amdgcn_readfirstlane((swz << 3) | wv);
  int b = pix >> 14, hw = pix & (HWs - 1);
  int h = hw >> 7, w = hw & 127;
  int dh = lane / 7 - 3, dw = lane % 7 - 3;
  bool lact = lane < 49;
  int hn = h + dh, wn = w + dw;
  bool inb = lact && ((unsigned)hn < 128u) && ((unsigned)wn < 128u);
  int hwn = inb ? ((hn << 7) | wn) : hw;
  size_t bb = (size_t)b << 14;

  // hoist scalar branch conditions (resolve while gathers are in flight)
  int gtc = __builtin_amdgcn_readfirstlane(gt[bb + hw]);
  u32 mixu = __builtin_amdgcn_readfirstlane(__float_as_uint(mix[bb + hw]));

  float psum = 0, ssum = 0, posa = 0, nega = 0, pcntW = 0, vcntW = 0, cntW = 0;

  // ---- source cosine sim ----
  if (gtc != 255) {
    const uint4* sc = (const uint4*)(fsrc + (bb + hw) * FSTR);
    const uint4* sn = (const uint4*)(fsrc + (bb + hwn) * FSTR);
    float d0 = 0, d1 = 0, d2 = 0, d3 = 0;
#pragma unroll
    for (int q = 0; q < 8; q += 4) {
      uint4 a0 = sc[q], b0 = sn[q], a1 = sc[q+1], b1 = sn[q+1];
      uint4 a2 = sc[q+2], b2 = sn[q+2], a3 = sc[q+3], b3 = sn[q+3];
      d0 = fd(a0.x,b0.x,d0); d0 = fd(a0.y,b0.y,d0); d0 = fd(a0.z,b0.z,d0); d0 = fd(a0.w,b0.w,d0);
      d1 = fd(a1.x,b1.x,d1); d1 = fd(a1.y,b1.y,d1); d1 = fd(a1.z,b1.z,d1); d1 = fd(a1.w,b1.w,d1);
      d2 = fd(a2.x,b2.x,d2); d2 = fd(a2.y,b2.y,d2); d2 = fd(a2.z,b2.z,d2); d2 = fd(a2.w,b2.w,d2);
      d3 = fd(a3.x,b3.x,d3); d3 = fd(a3.y,b3.y,d3); d3 = fd(a3.z,b3.z,d3); d3 = fd(a3.w,b3.w,d3);
    }
    float sims = inb ? ((d0 + d1) + (d2 + d3)) : 0.f;  // zero-pad unfold -> sim 0
    int gtn = inb ? gt[bb + hwn] : 0;                  // zero-pad unfold -> gt 0
    bool pos = (gtn == gtc);
    if (lact) { ssum = sims; if (pos) psum = sims; }
    u64 mk = __ballot(lact && pos);
    pcntW = (float)__popcll(mk);
    vcntW = 1.f;
  }

  // ---- target branch (wave-uniform) ----
  if (__uint_as_float(mixu) < 0.5f) {
    const uint4* ec = (const uint4*)(fema + (bb + hw) * FSTR);
    const uint4* en = (const uint4*)(fema + (bb + hwn) * FSTR);
    float d0 = 0, d1 = 0, d2 = 0, d3 = 0;
#pragma unroll
    for (int q = 0; q < 8; q += 4) {
      uint4 a0 = ec[q], b0 = en[q], a1 = ec[q+1], b1 = en[q+1];
      uint4 a2 = ec[q+2], b2 = en[q+2], a3 = ec[q+3], b3 = en[q+3];
      d0 = fd(a0.x,b0.x,d0); d0 = fd(a0.y,b0.y,d0); d0 = fd(a0.z,b0.z,d0); d0 = fd(a0.w,b0.w,d0);
      d1 = fd(a1.x,b1.x,d1); d1 = fd(a1.y,b1.y,d1); d1 = fd(a1.z,b1.z,d1); d1 = fd(a1.w,b1.w,d1);
      d2 = fd(a2.x,b2.x,d2); d2 = fd(a2.y,b2.y,d2); d2 = fd(a2.z,b2.z,d2); d2 = fd(a2.w,b2.w,d2);
      d3 = fd(a3.x,b3.x,d3); d3 = fd(a3.y,b3.y,d3); d3 = fd(a3.z,b3.z,d3); d3 = fd(a3.w,b3.w,d3);
    }
    float dote = (d0 + d1) + (d2 + d3);
    const uint4* pc = (const uint4*)(pt + (bb + hw) * PSTR);
    const uint4* pn = (const uint4*)(pt + (bb + hwn) * PSTR);
    float p0 = 0, p1 = 0, p2 = 0;
    {
      uint4 a0 = pc[0], b0 = pn[0], a1 = pc[1], b1 = pn[1], a2 = pc[2], b2 = pn[2];
      p0 = fd(a0.x,b0.x,p0); p0 = fd(a0.y,b0.y,p0); p0 = fd(a0.z,b0.z,p0); p0 = fd(a0.w,b0.w,p0);
      p1 = fd(a1.x,b1.x,p1); p1 = fd(a1.y,b1.y,p1); p1 = fd(a1.z,b1.z,p1); p1 = fd(a1.w,b1.w,p1);
      p2 = fd(a2.x,b2.x,p2); p2 = fd(a2.y,b2.y,p2); p2 = fd(a2.z,b2.z,p2); p2 = fd(a2.w,b2.w,p2);
    }
    float dotp = (p0 + p1) + p2;

    float v  = inb ? dote : 0.f;
    float cp = inb ? dotp : (1.0f / 19.f);

    // sortable key: monotone f32 bits + lane in LSBs (all 49 keys distinct)
    u32 bits = __float_as_uint(v);
    u32 mono = (bits & 0x80000000u) ? ~bits : (bits | 0x80000000u);
    u64 k64 = ((u64)mono << 6) | (u32)lane;
    ksh[wv][lane] = k64;
    int rd = 0;
#pragma unroll
    for (int j = 0; j < 48; j += 2) {
      ulonglong2 q = *(const ulonglong2*)&ksh[wv][j];
      rd += (q.x > k64);
      rd += (q.y > k64);
    }
    rd += (ksh[wv][48] > k64);
    if (lact) {
      if (rd < 9)   posa = v * cp;                     // top-9 most similar
      if (rd >= 41) nega = (1.f - v) * (1.f - cp);     // bottom-8 (rank_asc = 48-rd < 8)
    }
    cntW = 1.f;
  }

  // butterfly reduce 4 float sums
#pragma unroll
  for (int off = 32; off; off >>= 1) {
    psum += __shfl_xor(psum, off); ssum += __shfl_xor(ssum, off);
    posa += __shfl_xor(posa, off); nega += __shfl_xor(nega, off);
  }
  if (lane == 0) {
    sacc[wv][0] = psum;  sacc[wv][1] = pcntW; sacc[wv][2] = ssum;
    sacc[wv][3] = posa;  sacc[wv][4] = nega;  sacc[wv][5] = vcntW;
    sacc[wv][6] = cntW;  sacc[wv][7] = 0.f;
  }
  __syncthreads();
  if (t < 8) {
    float s = 0.f;
#pragma unroll
    for (int k = 0; k < 8; k++) s += sacc[k][t];
    partials[(size_t)bid * 8 + t] = s;
  }
  // ---- last-block finish ----
  __threadfence();
  if (t == 0) is_last = (atomicAdd(ticket, 1u) == (u32)(gridDim.x - 1));
  __syncthreads();
  if (is_last) {
    __threadfence();
    float s0=0,s1=0,s2=0,s3=0,s4=0,s5=0,s6=0;
    for (int r = t; r < STBLK; r += 512) {
      const float4* p = (const float4*)(partials + (size_t)r * 8);
      float4 x = p[0], y = p[1];
      s0 += x.x; s1 += x.y; s2 += x.z; s3 += x.w;
      s4 += y.x; s5 += y.y; s6 += y.z;
    }
#pragma unroll
    for (int off = 32; off; off >>= 1) {
      s0 += __shfl_xor(s0, off); s1 += __shfl_xor(s1, off);
      s2 += __shfl_xor(s2, off); s3 += __shfl_xor(s3, off);
      s4 += __shfl_xor(s4, off); s5 += __shfl_xor(s5, off);
      s6 += __shfl_xor(s6, off);
    }
    if (lane == 0) {
      sacc[wv][0]=s0; sacc[wv][1]=s1; sacc[wv][2]=s2; sacc[wv][3]=s3;
      sacc[wv][4]=s4; sacc[wv][5]=s5; sacc[wv][6]=s6;
    }
    __syncthreads();
    if (t == 0) {
      float a[7];
#pragma unroll
      for (int c = 0; c < 7; c++) {
        float s = 0.f;
#pragma unroll
        for (int k = 0; k < 8; k++) s += sacc[k][c];
        a[c] = s;
      }
      float psumT = a[0], pcntT = a[1], ssumT = a[2];
      float posaT = a[3], negaT = a[4], vcntT = a[5], cntT = a[6];
      float nsumT = ssumT - psumT;
      float ncntT = 49.f * vcntT - pcntT;
      out[0] = -(psumT / fmaxf(pcntT, 1.0f));
      out[1] =  (nsumT / fmaxf(ncntT, 1.0f));
      out[2] = -(posaT / fmaxf(9.0f * cntT, 1.0f));
      out[3] = -(negaT / fmaxf(8.0f * cntT, 1.0f));
    }
  }
}

extern "C" void kernel_launch(void* const* d_in, const int* in_sizes, int n_in,
                              void* d_out, int out_size, void* d_ws, size_t ws_size,
                              hipStream_t stream) {
  const float* logits = (const float*)d_in[0];
  const int*   gt     = (const int*)  d_in[1];
  const float* xema   = (const float*)d_in[2];
  const float* xsrc   = (const float*)d_in[3];
  const float* mix    = (const float*)d_in[4];
  float* out = (float*)d_out;

  float* partials = (float*)d_ws;                                 // STBLK*8 f32 = 128 KB
  u32*  ticket = (u32*)((char*)d_ws + STBLK * 8 * sizeof(float)); // 1 u32 (+pad to 16B)
  u16* fsrc = (u16*)((char*)ticket + 16);                         // NPIX*FSTR f16 = 4.5 MB
  u16* fema = fsrc + (size_t)NPIX * FSTR;                         // 4.5 MB
  u16* pt   = fema + (size_t)NPIX * FSTR;                         // NPIX*PSTR f16 = 1.5 MB

  hipMemsetAsync(ticket, 0, sizeof(u32), stream);
  pre_kernel<<<1152, 256, 0, stream>>>(logits, xsrc, xema, fsrc, fema, pt);
  st_kernel<<<STBLK, 512, 0, stream>>>(fsrc, fema, pt, gt, mix, partials, ticket, out);
}

// Round 6
// 48.059 us; speedup vs baseline: 11.5068x; 11.5068x over previous
//
#include <hip/hip_runtime.h>
#include <math.h>

typedef unsigned short u16;
typedef unsigned int   u32;
typedef unsigned long long u64;

#define Bb   2
#define Cc   19
#define Hh   128
#define Ww   128
#define CHc  64
#define HWs  16384
#define NPIX 32768
#define EPSf 1e-8f
#define FSTR 72               // half stride for features (64 real + 8 zero pad), 144 B
#define PSTR 24               // half stride for probs (19 real + 5 zero pad), 48 B

typedef _Float16 h2 __attribute__((ext_vector_type(2)));

__device__ inline float fd(u32 a, u32 b, float c) {
  h2 ha = __builtin_bit_cast(h2, a);
  h2 hb = __builtin_bit_cast(h2, b);
#if __has_builtin(__builtin_amdgcn_fdot2)
  return __builtin_amdgcn_fdot2(ha, hb, c, false);
#else
  return c + (float)ha[0] * (float)hb[0] + (float)ha[1] * (float)hb[1];
#endif
}

__device__ inline u32 pk(float a, float b) {
  h2 h; h[0] = (_Float16)a; h[1] = (_Float16)b;
  return __builtin_bit_cast(u32, h);
}

// ---------- PRE: feat normalize+transpose (blocks 0..1023) | softmax (1024..1151) ----------
__global__ __launch_bounds__(256) void pre_kernel(
    const float* __restrict__ logits,
    const float* __restrict__ xsrc, const float* __restrict__ xema,
    u16* __restrict__ osrc, u16* __restrict__ oema, u16* __restrict__ pt) {
  __shared__ float smem[5376];
  int bid = blockIdx.x;
  int t = threadIdx.x;

  if (bid < 1024) {
    float* tile = smem;                 // 64*65
    float* part = smem + 4160;          // 256
    float* invn = smem + 4416;          // 64
    int xb = bid & 255, b = (bid >> 8) & 1, z = bid >> 9;
    const float* in = z ? xema : xsrc;
    u16* out = z ? oema : osrc;
    int pix0 = xb * 64;
    int w = t >> 6, l = t & 63;

    const float* src = in + (size_t)b * CHc * HWs + pix0;
#pragma unroll
    for (int cc = 0; cc < 16; cc++) {
      int c = cc * 4 + w;
      tile[c * 65 + l] = src[(size_t)c * HWs + l];
    }
    __syncthreads();
    float s = 0.f;
#pragma unroll
    for (int c = w * 16; c < w * 16 + 16; c++) { float a = tile[c * 65 + l]; s += a * a; }
    part[w * 64 + l] = s;
    __syncthreads();
    if (t < 64) {
      float n = part[t] + part[64 + t] + part[128 + t] + part[192 + t];
      invn[t] = 1.0f / fmaxf(sqrtf(n), EPSf);
    }
    __syncthreads();
    for (int i = t; i < 576; i += 256) {
      int px = i / 9, q = i - px * 9;
      float iv = invn[px];
      float v[8];
#pragma unroll
      for (int k = 0; k < 8; k++) {
        int c = q * 8 + k;
        v[k] = (c < CHc) ? tile[c * 65 + px] * iv : 0.f;
      }
      uint4 u = make_uint4(pk(v[0], v[1]), pk(v[2], v[3]), pk(v[4], v[5]), pk(v[6], v[7]));
      *((uint4*)(out + (size_t)(b * HWs + pix0 + px) * FSTR) + q) = u;
    }
  } else {
    float* lp = smem;                   // 256*21
    int pb = bid - 1024;
    int gpix = pb * 256 + t;
    int b = gpix >> 14, hw = gpix & (HWs - 1);
    const float* lg = logits + (size_t)b * Cc * HWs + hw;
    float v[Cc]; float m = -INFINITY;
#pragma unroll
    for (int c = 0; c < Cc; c++) { v[c] = lg[(size_t)c * HWs]; m = fmaxf(m, v[c]); }
    float s = 0.f;
#pragma unroll
    for (int c = 0; c < Cc; c++) { v[c] = expf(v[c] - m); s += v[c]; }
    float inv = 1.0f / s;
#pragma unroll
    for (int c = 0; c < Cc; c++) lp[t * 21 + c] = v[c] * inv;
    __syncthreads();
    u16* ob = pt + (size_t)pb * 256 * PSTR;
    for (int i = t; i < 768; i += 256) {
      int px = i / 3, q = i - px * 3;
      float v8[8];
#pragma unroll
      for (int k = 0; k < 8; k++) {
        int c = q * 8 + k;
        v8[k] = (c < Cc) ? lp[px * 21 + c] : 0.f;
      }
      uint4 u = make_uint4(pk(v8[0], v8[1]), pk(v8[2], v8[3]), pk(v8[4], v8[5]), pk(v8[6], v8[7]));
      *((uint4*)(ob + (size_t)px * PSTR) + q) = u;
    }
  }
}

// ---------- ST: fused src-sim + trg rank-select, ONE pixel per wave ----------
// Straight-line gather issue: src + ema neighbor loads all in flight before dots.
__global__ __launch_bounds__(256, 4) void st_kernel(
    const u16* __restrict__ fsrc, const u16* __restrict__ fema,
    const u16* __restrict__ pt, const int* __restrict__ gt,
    const float* __restrict__ mix, float* __restrict__ partials) {
  __shared__ u64 ksh[4][66];
  __shared__ float sacc[4][8];
  int bid = blockIdx.x;
  int swz = ((bid & 7) << 10) | (bid >> 3);        // 8192 % 8 == 0: bijective
  int t = threadIdx.x, wv = t >> 6, lane = t & 63;
  int pix = __builtin_amdgcn_readfirstlane((swz << 2) | wv);
  int b = pix >> 14, hw = pix & (HWs - 1);
  int h = hw >> 7, w = hw & 127;
  int dh = lane / 7 - 3, dw = lane % 7 - 3;
  bool lact = lane < 49;
  int hn = h + dh, wn = w + dw;
  bool inb = lact && ((unsigned)hn < 128u) && ((unsigned)wn < 128u);
  int hwn = inb ? ((hn << 7) | wn) : hw;
  size_t bb = (size_t)b << 14;

  // scalar branch conditions (uniform loads -> SGPR)
  int gtc = __builtin_amdgcn_readfirstlane(gt[bb + hw]);
  u32 mixu = __builtin_amdgcn_readfirstlane(__float_as_uint(mix[bb + hw]));
  bool do_t = __uint_as_float(mixu) < 0.5f;        // wave-uniform

  const uint4* sc = (const uint4*)(fsrc + (bb + hw) * FSTR);   // uniform center
  const uint4* sn = (const uint4*)(fsrc + (bb + hwn) * FSTR);  // per-lane gather
  const uint4* ec = (const uint4*)(fema + (bb + hw) * FSTR);
  const uint4* en = (const uint4*)(fema + (bb + hwn) * FSTR);

  // ---- issue all neighbor gathers up front ----
  uint4 S[9], E[9];
#pragma unroll
  for (int q = 0; q < 9; q++) S[q] = sn[q];
  if (do_t) {
#pragma unroll
    for (int q = 0; q < 9; q++) E[q] = en[q];
  }

  float psum = 0, ssum = 0, posa = 0, nega = 0, pcntW = 0, vcntW = 0, cntW = 0;

  // ---- source cosine sim (consumes S while E still in flight) ----
  if (gtc != 255) {
    float d0 = 0, d1 = 0, d2 = 0, d3 = 0;
#pragma unroll
    for (int q = 0; q < 8; q += 4) {
      uint4 a0 = sc[q], a1 = sc[q+1], a2 = sc[q+2], a3 = sc[q+3];
      d0 = fd(a0.x,S[q].x,d0);   d0 = fd(a0.y,S[q].y,d0);   d0 = fd(a0.z,S[q].z,d0);   d0 = fd(a0.w,S[q].w,d0);
      d1 = fd(a1.x,S[q+1].x,d1); d1 = fd(a1.y,S[q+1].y,d1); d1 = fd(a1.z,S[q+1].z,d1); d1 = fd(a1.w,S[q+1].w,d1);
      d2 = fd(a2.x,S[q+2].x,d2); d2 = fd(a2.y,S[q+2].y,d2); d2 = fd(a2.z,S[q+2].z,d2); d2 = fd(a2.w,S[q+2].w,d2);
      d3 = fd(a3.x,S[q+3].x,d3); d3 = fd(a3.y,S[q+3].y,d3); d3 = fd(a3.z,S[q+3].z,d3); d3 = fd(a3.w,S[q+3].w,d3);
    }
    float sims = inb ? ((d0 + d1) + (d2 + d3)) : 0.f;  // zero-pad unfold -> sim 0
    int gtn = inb ? gt[bb + hwn] : 0;                  // zero-pad unfold -> gt 0
    bool pos = (gtn == gtc);
    if (lact) { ssum = sims; if (pos) psum = sims; }
    u64 mk = __ballot(lact && pos);
    pcntW = (float)__popcll(mk);
    vcntW = 1.f;
  }

  // ---- target branch (wave-uniform) ----
  if (do_t) {
    // prob gathers issue here, overlapping the ema dot below
    const uint4* pc = (const uint4*)(pt + (bb + hw) * PSTR);
    const uint4* pn = (const uint4*)(pt + (bb + hwn) * PSTR);
    uint4 P0 = pn[0], P1 = pn[1], P2 = pn[2];

    float d0 = 0, d1 = 0, d2 = 0, d3 = 0;
#pragma unroll
    for (int q = 0; q < 8; q += 4) {
      uint4 a0 = ec[q], a1 = ec[q+1], a2 = ec[q+2], a3 = ec[q+3];
      d0 = fd(a0.x,E[q].x,d0);   d0 = fd(a0.y,E[q].y,d0);   d0 = fd(a0.z,E[q].z,d0);   d0 = fd(a0.w,E[q].w,d0);
      d1 = fd(a1.x,E[q+1].x,d1); d1 = fd(a1.y,E[q+1].y,d1); d1 = fd(a1.z,E[q+1].z,d1); d1 = fd(a1.w,E[q+1].w,d1);
      d2 = fd(a2.x,E[q+2].x,d2); d2 = fd(a2.y,E[q+2].y,d2); d2 = fd(a2.z,E[q+2].z,d2); d2 = fd(a2.w,E[q+2].w,d2);
      d3 = fd(a3.x,E[q+3].x,d3); d3 = fd(a3.y,E[q+3].y,d3); d3 = fd(a3.z,E[q+3].z,d3); d3 = fd(a3.w,E[q+3].w,d3);
    }
    float dote = (d0 + d1) + (d2 + d3);
    float p0 = 0, p1 = 0, p2 = 0;
    {
      uint4 a0 = pc[0], a1 = pc[1], a2 = pc[2];
      p0 = fd(a0.x,P0.x,p0); p0 = fd(a0.y,P0.y,p0); p0 = fd(a0.z,P0.z,p0); p0 = fd(a0.w,P0.w,p0);
      p1 = fd(a1.x,P1.x,p1); p1 = fd(a1.y,P1.y,p1); p1 = fd(a1.z,P1.z,p1); p1 = fd(a1.w,P1.w,p1);
      p2 = fd(a2.x,P2.x,p2); p2 = fd(a2.y,P2.y,p2); p2 = fd(a2.z,P2.z,p2); p2 = fd(a2.w,P2.w,p2);
    }
    float dotp = (p0 + p1) + p2;

    float v  = inb ? dote : 0.f;
    float cp = inb ? dotp : (1.0f / 19.f);

    // sortable key: monotone f32 bits + lane in LSBs (all 49 keys distinct)
    u32 bits = __float_as_uint(v);
    u32 mono = (bits & 0x80000000u) ? ~bits : (bits | 0x80000000u);
    u64 k64 = ((u64)mono << 6) | (u32)lane;
    ksh[wv][lane] = k64;
    int rd = 0;
#pragma unroll
    for (int j = 0; j < 48; j += 2) {
      ulonglong2 q = *(const ulonglong2*)&ksh[wv][j];
      rd += (q.x > k64);
      rd += (q.y > k64);
    }
    rd += (ksh[wv][48] > k64);
    if (lact) {
      if (rd < 9)   posa = v * cp;                     // top-9 most similar
      if (rd >= 41) nega = (1.f - v) * (1.f - cp);     // bottom-8 (rank_asc = 48-rd < 8)
    }
    cntW = 1.f;
  }

  // butterfly reduce 4 float sums
#pragma unroll
  for (int off = 32; off; off >>= 1) {
    psum += __shfl_xor(psum, off); ssum += __shfl_xor(ssum, off);
    posa += __shfl_xor(posa, off); nega += __shfl_xor(nega, off);
  }
  if (lane == 0) {
    sacc[wv][0] = psum;  sacc[wv][1] = pcntW; sacc[wv][2] = ssum;
    sacc[wv][3] = posa;  sacc[wv][4] = nega;  sacc[wv][5] = vcntW;
    sacc[wv][6] = cntW;  sacc[wv][7] = 0.f;
  }
  __syncthreads();
  if (t < 8) {
    partials[(size_t)bid * 8 + t] = sacc[0][t] + sacc[1][t] + sacc[2][t] + sacc[3][t];
  }
}

// ---------- F: reduce 8192 partials, combine ----------
__global__ __launch_bounds__(256) void finish_kernel(
    const float* __restrict__ partials, float* __restrict__ out) {
  int t = threadIdx.x, lane = t & 63, wv = t >> 6;
  float s0=0,s1=0,s2=0,s3=0,s4=0,s5=0,s6=0;
  for (int r = t; r < 8192; r += 256) {
    const float4* p = (const float4*)(partials + (size_t)r * 8);
    float4 x = p[0], y = p[1];
    s0 += x.x; s1 += x.y; s2 += x.z; s3 += x.w;
    s4 += y.x; s5 += y.y; s6 += y.z;
  }
#pragma unroll
  for (int off = 32; off; off >>= 1) {
    s0 += __shfl_xor(s0, off); s1 += __shfl_xor(s1, off);
    s2 += __shfl_xor(s2, off); s3 += __shfl_xor(s3, off);
    s4 += __shfl_xor(s4, off); s5 += __shfl_xor(s5, off);
    s6 += __shfl_xor(s6, off);
  }
  __shared__ float sacc[4][8];
  if (lane == 0) {
    sacc[wv][0]=s0; sacc[wv][1]=s1; sacc[wv][2]=s2; sacc[wv][3]=s3;
    sacc[wv][4]=s4; sacc[wv][5]=s5; sacc[wv][6]=s6;
  }
  __syncthreads();
  if (t == 0) {
    float a[7];
#pragma unroll
    for (int c = 0; c < 7; c++) a[c] = sacc[0][c] + sacc[1][c] + sacc[2][c] + sacc[3][c];
    float psum = a[0], pcnt = a[1], ssum = a[2];
    float posa = a[3], nega = a[4], vcnt = a[5], cnt = a[6];
    float nsum = ssum - psum;
    float ncnt = 49.f * vcnt - pcnt;
    out[0] = -(psum / fmaxf(pcnt, 1.0f));
    out[1] =  (nsum / fmaxf(ncnt, 1.0f));
    out[2] = -(posa / fmaxf(9.0f * cnt, 1.0f));
    out[3] = -(nega / fmaxf(8.0f * cnt, 1.0f));
  }
}

extern "C" void kernel_launch(void* const* d_in, const int* in_sizes, int n_in,
                              void* d_out, int out_size, void* d_ws, size_t ws_size,
                              hipStream_t stream) {
  const float* logits = (const float*)d_in[0];
  const int*   gt     = (const int*)  d_in[1];
  const float* xema   = (const float*)d_in[2];
  const float* xsrc   = (const float*)d_in[3];
  const float* mix    = (const float*)d_in[4];
  float* out = (float*)d_out;

  float* partials = (float*)d_ws;                                 // 8192*8 f32 = 256 KB
  u16* fsrc = (u16*)((char*)d_ws + 8192 * 8 * sizeof(float));     // NPIX*FSTR f16 = 4.5 MB
  u16* fema = fsrc + (size_t)NPIX * FSTR;                         // 4.5 MB
  u16* pt   = fema + (size_t)NPIX * FSTR;                         // NPIX*PSTR f16 = 1.5 MB

  pre_kernel<<<1152, 256, 0, stream>>>(logits, xsrc, xema, fsrc, fema, pt);
  st_kernel<<<8192, 256, 0, stream>>>(fsrc, fema, pt, gt, mix, partials);
  finish_kernel<<<1, 256, 0, stream>>>(partials, out);
}